// Round 1
// 332.048 us; speedup vs baseline: 1.0153x; 1.0153x over previous
//
#include <hip/hip_runtime.h>

// LIF scan: x[B,T,N] f32 -> spikes[B,T,N] f32
//   v = v + (x - v)/2 ; s = (v >= 1) ; v = s ? 0 : v
// Sequential in t only; B*N independent chains. Memory-bound streaming
// (~420 MB total traffic -> ~67 us floor at 6.3 TB/s).
//
// R1 change vs R0: float4 -> float2 chain granularity.
//   R0 had B*N/4 = 65536 threads = 4 waves/CU = 1 wave/SIMD: every HBM
//   load stall is exposed in-line (no co-resident wave on the SIMD), and
//   in-order vmcnt retire serializes next-iter loads behind prior stores.
//   float2 doubles TLP to 8 waves/CU (2/SIMD) at identical coalescing
//   (512B per wave-instruction, contiguous). Plus nontemporal hints:
//   both streams are touch-once, evict-first keeps L2 churn down.

typedef float vfloat2 __attribute__((ext_vector_type(2)));

constexpr int B = 64;
constexpr int T = 200;
constexpr int N = 4096;
constexpr int N2 = N / 2;  // 2048 float2 per (b,t) row

__global__ __launch_bounds__(256) void lif_kernel(const vfloat2* __restrict__ x,
                                                  vfloat2* __restrict__ out) {
    const int idx = blockIdx.x * blockDim.x + threadIdx.x;  // 0 .. B*N2-1
    const int b = idx >> 11;         // idx / N2
    const int n = idx & (N2 - 1);    // idx % N2

    const vfloat2* __restrict__ xp = x + (size_t)b * (T * N2) + n;
    vfloat2* __restrict__ op = out + (size_t)b * (T * N2) + n;

    vfloat2 v = {0.0f, 0.0f};

#pragma unroll 8
    for (int t = 0; t < T; ++t) {
        const vfloat2 xv = __builtin_nontemporal_load(xp + t * N2);
        // v = v + (x - v) * 0.5f  -- *0.5 is exact (power of two), so with
        // or without fma contraction this matches the f32 reference
        // bit-for-bit (verified absmax == 0.0 in R0 with this expression).
        vfloat2 vn = v;
        vn.x = vn.x + (xv.x - vn.x) * 0.5f;
        vn.y = vn.y + (xv.y - vn.y) * 0.5f;

        vfloat2 s;
        s.x = (vn.x >= 1.0f) ? 1.0f : 0.0f;
        s.y = (vn.y >= 1.0f) ? 1.0f : 0.0f;

        vn.x = (vn.x >= 1.0f) ? 0.0f : vn.x;
        vn.y = (vn.y >= 1.0f) ? 0.0f : vn.y;
        v = vn;

        __builtin_nontemporal_store(s, op + t * N2);
    }
}

extern "C" void kernel_launch(void* const* d_in, const int* in_sizes, int n_in,
                              void* d_out, int out_size, void* d_ws, size_t ws_size,
                              hipStream_t stream) {
    const vfloat2* x = (const vfloat2*)d_in[0];  // [B,T,N] f32
    // d_in[1] (threshold, 1xN) is unused by the reference math.
    vfloat2* out = (vfloat2*)d_out;

    const int threads = B * N2;        // 131072 chains (float2 granularity)
    const int block = 256;
    const int grid = threads / block;  // 512 blocks -> 2 blocks/CU, 8 waves/CU
    lif_kernel<<<grid, block, 0, stream>>>(x, out);
}